// Round 14
// baseline (166.728 us; speedup 1.0000x reference)
//
#include <hip/hip_runtime.h>
#include <hip/hip_bf16.h>

typedef __attribute__((ext_vector_type(8))) short short8v;   // 8 bf16
typedef __attribute__((ext_vector_type(4))) short short4v;   // 4 bf16
typedef __attribute__((ext_vector_type(4))) float f32x4;
typedef __attribute__((ext_vector_type(4))) int int4v;

#define NTOK  2048
#define NEMBD 768
#define DFF   3072
#define NEXP  8
#define MAXSLOT 5120          // 128-aligned per-expert regions, sum <= 5120
#define NT1 24                // DFF/128
#define NT2 6                 // NEMBD/128
#define MAXT1 40              // max 128-row tiles
#define MAXT2 80              // max 64-row tiles

// ---- workspace layout (bytes) ----
#define WS_XBF   0                                   // ushort [2048][768]
#define WS_GATES (WS_XBF + (size_t)NTOK*NEMBD*2)     // float  [2048][8]
#define WS_TE    (WS_GATES + NTOK*8*4)               // int    [2048][2]
#define WS_TW    (WS_TE + NTOK*2*4)                  // float  [2048][2]
#define WS_KL    (WS_TW + NTOK*2*4)                  // float  [2048]
#define WS_CTRL  (WS_KL + NTOK*4)                    // int[512]
#define WS_STOK  (WS_CTRL + 2048)                    // int    [MAXSLOT]
#define WS_TSLOT (WS_STOK + MAXSLOT*4)               // int    [2048][2]
#define WS_WFCT  (WS_TSLOT + NTOK*2*4)               // ushort [8][3072][768]  (obuf aliases this)
#define WS_WPT   (WS_WFCT + (size_t)NEXP*DFF*NEMBD*2)// ushort [8][768][3072]
#define WS_H     (WS_WPT + (size_t)NEXP*NEMBD*DFF*2) // ushort [MAXSLOT][3072]
#define WS_OBUF  WS_WFCT                             // float [MAXSLOT][768] aliases WfcT (dead after gemm1)

__device__ __forceinline__ unsigned short f2bf(float f) {
    union { float f; unsigned u; } v; v.f = f;
    unsigned r = v.u + 0x7fffu + ((v.u >> 16) & 1u);   // RNE
    return (unsigned short)(r >> 16);
}

__device__ __forceinline__ void gload16(const void* g, void* l) {
    __builtin_amdgcn_global_load_lds(
        (const __attribute__((address_space(1))) void*)g,
        (__attribute__((address_space(3))) void*)l, 16, 0, 0);
}

// ---- transpose tile: in [E][R][C] f32 -> out [E][C][R] bf16 ----
// tile 128 k-rows x 64 n-cols; LDS [n=64][slot=32 of 4 bf16], row stride 264B (+8 pad),
// slot XOR (n>>3)&3. NT loads (ext-vector f32x4) on the single-use fp32 weight stream.
#define SROW 264
__device__ __forceinline__ void transpose_tile(
    const float* __restrict__ in, unsigned short* __restrict__ out,
    int R, int C, int tilesC, int tb, char* sT, int tid)
{
    int e = tb / 288, rem = tb % 288;
    int rt = rem / tilesC, ct = rem % tilesC;
    int ng = tid & 7, kg = tid >> 3;          // ng: n-octet (8), kg: k-quad (0..31)
    const float* src = in + ((size_t)e * R + rt * 128 + kg * 4) * C + ct * 64 + ng * 8;
    unsigned short cb[8][4];
    #pragma unroll
    for (int i = 0; i < 4; ++i) {
        f32x4 a = __builtin_nontemporal_load((const f32x4*)&src[(size_t)i * C]);
        f32x4 b = __builtin_nontemporal_load((const f32x4*)&src[(size_t)i * C + 4]);
        cb[0][i] = f2bf(a[0]); cb[1][i] = f2bf(a[1]); cb[2][i] = f2bf(a[2]); cb[3][i] = f2bf(a[3]);
        cb[4][i] = f2bf(b[0]); cb[5][i] = f2bf(b[1]); cb[6][i] = f2bf(b[2]); cb[7][i] = f2bf(b[3]);
    }
    #pragma unroll
    for (int j = 0; j < 8; ++j) {
        int n = ng * 8 + j;
        int sl = kg ^ ((n >> 3) & 3);         // bijective per n
        *(short4v*)(sT + n * SROW + sl * 8) = *(const short4v*)&cb[j][0];
    }
    __syncthreads();
    int n2 = tid >> 2, cs = tid & 3;          // n2: 0..63, cs: k-chunk (32 elems)
    unsigned short tmp[32];
    #pragma unroll
    for (int i = 0; i < 8; ++i) {
        int sl = (cs * 8 + i) ^ ((n2 >> 3) & 3);
        *(short4v*)&tmp[i * 4] = *(const short4v*)(sT + n2 * SROW + sl * 8);
    }
    unsigned short* dstp = out + ((size_t)e * C + ct * 64 + n2) * R + rt * 128 + cs * 32;
    #pragma unroll
    for (int q = 0; q < 4; ++q)
        *(int4v*)&dstp[q * 8] = *(const int4v*)&tmp[q * 8];
}

// ---------------- front: router (0..511) + Wfc T (512..2815) + Wp T (2816..5119) ----------
__global__ __launch_bounds__(256) void k_front(
    const float* __restrict__ x, const float* __restrict__ WgP, const float* __restrict__ WgQ,
    const float* __restrict__ Wfc, const float* __restrict__ Wpj,
    unsigned short* __restrict__ WfcT, unsigned short* __restrict__ WpT,
    unsigned short* __restrict__ xbf, float* __restrict__ gates,
    int* __restrict__ te, float* __restrict__ tw, float* __restrict__ kl_tok)
{
    __shared__ char sT[64 * SROW];   // 16.9 KB
    int tid = threadIdx.x;
    int bid = blockIdx.x;
    if (bid >= 2816) {
        transpose_tile(Wpj, WpT, DFF, NEMBD, 12, bid - 2816, sT, tid);
        return;
    }
    if (bid >= 512) {
        transpose_tile(Wfc, WfcT, NEMBD, DFF, 48, bid - 512, sT, tid);
        return;
    }
    // -------- router: one wave per token, no global atomics --------
    int rb = bid;   // 0..511
    int wave = tid >> 6, lane = tid & 63;
    int t = rb * 4 + wave;
    int b = t >> 10, l = t & 1023;
    int lf = l + 2; if (lf > 1023) lf = 1023;           // lookforward pad-with-last
    const float* xr = x + (size_t)t * NEMBD;
    const float* xf = x + (size_t)((b << 10) + lf) * NEMBD;
    int e = lane & 7, kg = lane >> 3;

    float accP = 0.f, accQ = 0.f;
    #pragma unroll 8
    for (int i = 0; i < 96; ++i) {
        int k = kg + 8 * i;
        accP += xr[k] * WgP[k * NEXP + e];
        accQ += xf[k] * WgQ[k * NEXP + e];
    }
    #pragma unroll
    for (int off = 8; off < 64; off <<= 1) {
        accP += __shfl_xor(accP, off);
        accQ += __shfl_xor(accQ, off);
    }
    float mq = accQ, mp = accP;
    #pragma unroll
    for (int off = 1; off < 8; off <<= 1) {
        mq = fmaxf(mq, __shfl_xor(mq, off));
        mp = fmaxf(mp, __shfl_xor(mp, off));
    }
    float gq = __expf(accQ - mq), gp = __expf(accP - mp);
    float se = gq, sp = gp;
    #pragma unroll
    for (int off = 1; off < 8; off <<= 1) {
        se += __shfl_xor(se, off);
        sp += __shfl_xor(sp, off);
    }
    float v0 = gq; int e0 = e;
    #pragma unroll
    for (int off = 1; off < 8; off <<= 1) {
        float ov = __shfl_xor(v0, off); int oe = __shfl_xor(e0, off);
        if (ov > v0 || (ov == v0 && oe < e0)) { v0 = ov; e0 = oe; }
    }
    float vx = (e == e0) ? -1.f : gq;
    float v1 = vx; int e1 = e;
    #pragma unroll
    for (int off = 1; off < 8; off <<= 1) {
        float ov = __shfl_xor(v1, off); int oe = __shfl_xor(e1, off);
        if (ov > v1 || (ov == v1 && oe < e1)) { v1 = ov; e1 = oe; }
    }
    float lq = (accQ - mq) - logf(se);
    float lp = (accP - mp) - logf(sp);
    float kl = __expf(lq) * (lq - lp);
    #pragma unroll
    for (int off = 1; off < 8; off <<= 1) kl += __shfl_xor(kl, off);

    if (lane < 8) gates[t * NEXP + e] = gq / se;
    if (lane == 0) {
        float s2 = v0 + v1;
        te[t * 2] = e0; te[t * 2 + 1] = e1;
        tw[t * 2] = v0 / s2; tw[t * 2 + 1] = v1 / s2;
        kl_tok[t] = kl;
    }
    // x -> bf16 for this block's 4 token rows
    const float4* xs4 = (const float4*)(x + (size_t)rb * 4 * NEMBD);
    ushort4* xd4 = (ushort4*)(xbf + (size_t)rb * 4 * NEMBD);
    for (int i = tid; i < 4 * NEMBD / 4; i += 256) {
        float4 v = xs4[i];
        ushort4 o;
        o.x = f2bf(v.x); o.y = f2bf(v.y); o.z = f2bf(v.z); o.w = f2bf(v.w);
        xd4[i] = o;
    }
}

// ---------------- sched: histogram + offsets + tile tables + slot lists (1 block) ---------
// ctrl: [0..7] counts, [16..23] expert base, [24] total, [25] nt1, [26] nt2,
//       [64..103] t1 (e<<16|mt), [128..207] t2
__global__ __launch_bounds__(256) void k_sched(
    const int* __restrict__ te, int* __restrict__ ctrl,
    int* __restrict__ stok, int* __restrict__ tslot)
{
    __shared__ int cur[NEXP];
    __shared__ int cnt_s[NEXP];
    __shared__ int sOff[NEXP];
    int tid = threadIdx.x, lane = tid & 63;
    if (tid < NEXP) { cur[tid] = 0; cnt_s[tid] = 0; }
    for (int i = tid; i < MAXSLOT; i += 256) stok[i] = 0;
    __syncthreads();
    int cc[NEXP];
    #pragma unroll
    for (int e = 0; e < NEXP; ++e) cc[e] = 0;
    for (int i = tid; i < NTOK * 2; i += 256) {
        int e = te[i];
        #pragma unroll
        for (int q = 0; q < NEXP; ++q) cc[q] += (e == q) ? 1 : 0;
    }
    #pragma unroll
    for (int e = 0; e < NEXP; ++e) {
        int v = cc[e];
        #pragma unroll
        for (int off = 32; off; off >>= 1) v += __shfl_xor(v, off);
        if (lane == 0) atomicAdd(&cnt_s[e], v);
    }
    __syncthreads();
    if (tid == 0) {
        int off = 0, n1 = 0, n2 = 0;
        for (int e = 0; e < NEXP; ++e) {
            int cnt = cnt_s[e];
            ctrl[e] = cnt;
            ctrl[16 + e] = off; sOff[e] = off;
            int t128 = (cnt + 127) >> 7;
            for (int m = 0; m < t128; ++m)     ctrl[64 + n1++]  = (e << 16) | m;
            for (int m = 0; m < 2 * t128; ++m) ctrl[128 + n2++] = (e << 16) | m;
            off += t128 << 7;
        }
        ctrl[24] = off; ctrl[25] = n1; ctrl[26] = n2;
    }
    __syncthreads();
    for (int t = tid; t < NTOK; t += 256) {
        #pragma unroll
        for (int k = 0; k < 2; ++k) {
            int e = te[t * 2 + k];
            int s = atomicAdd(&cur[e], 1);
            int flat = sOff[e] + s;
            stok[flat] = t; tslot[t * 2 + k] = flat;
        }
    }
}

// ---------------- GEMM1: H = relu(Xg @ WfcT^T)^2, 128x128 tile, BK=64, XOR-swizzled LDS ----
__global__ __launch_bounds__(256) void k_gemm1(
    const unsigned short* __restrict__ xbf, const unsigned short* __restrict__ WfcT,
    const int* __restrict__ ctrl, const int* __restrict__ slot_tok,
    unsigned short* __restrict__ H)
{
    int bx = blockIdx.x;                      // grid = MAXT1*NT1 = 960
    int swz = (bx & 7) * (MAXT1 * NT1 / 8) + (bx >> 3);
    int nt = swz / MAXT1, tI = swz % MAXT1;
    if (tI >= ctrl[25]) return;
    int pk = ctrl[64 + tI];
    int e = pk >> 16, mt = pk & 0xffff;
    int base = ctrl[16 + e] + (mt << 7);

    __shared__ unsigned short sAB[2 * 128 * 64];   // sA | sB, reused as sC[128][128]
    unsigned short* sA = sAB;
    unsigned short* sB = sAB + 128 * 64;

    int tid = threadIdx.x, w = tid >> 6, lane = tid & 63;
    int wr = w >> 1, wc = w & 1;

    int swsub = (((lane & 7) ^ ((lane >> 3) & 7)) << 3);
    const unsigned short* wfc = WfcT + ((size_t)e * DFF + nt * 128) * NEMBD;
    const unsigned short* aptr[4]; const unsigned short* bptr[4];
    #pragma unroll
    for (int i = 0; i < 4; ++i) {
        int r = i * 32 + w * 8 + (lane >> 3);
        aptr[i] = xbf + (size_t)slot_tok[base + r] * NEMBD + swsub;
        bptr[i] = wfc + (size_t)r * NEMBD + swsub;
    }

    f32x4 acc[4][4];
    #pragma unroll
    for (int i = 0; i < 4; ++i)
        #pragma unroll
        for (int j = 0; j < 4; ++j) acc[i][j] = (f32x4){0.f, 0.f, 0.f, 0.f};

    int rsw = (lane & 7) << 3;
    for (int kk = 0; kk < NEMBD; kk += 64) {
        #pragma unroll
        for (int i = 0; i < 4; ++i) {
            gload16(aptr[i] + kk, &sA[(i * 256 + w * 64) * 8]);
            gload16(bptr[i] + kk, &sB[(i * 256 + w * 64) * 8]);
        }
        __syncthreads();
        #pragma unroll
        for (int kh = 0; kh < 2; ++kh) {
            int c = (kh * 32 + ((lane >> 4) << 3)) ^ rsw;
            short8v af[4], bfv[4];
            #pragma unroll
            for (int m = 0; m < 4; ++m)
                af[m] = *(const short8v*)&sA[(wr * 64 + m * 16 + (lane & 15)) * 64 + c];
            #pragma unroll
            for (int n = 0; n < 4; ++n)
                bfv[n] = *(const short8v*)&sB[(wc * 64 + n * 16 + (lane & 15)) * 64 + c];
            #pragma unroll
            for (int m = 0; m < 4; ++m)
                #pragma unroll
                for (int n = 0; n < 4; ++n)
                    acc[m][n] = __builtin_amdgcn_mfma_f32_16x16x32_bf16(af[m], bfv[n], acc[m][n], 0, 0, 0);
        }
        __syncthreads();
    }

    unsigned short* sC = sAB;   // [128][128]
    #pragma unroll
    for (int m = 0; m < 4; ++m)
        #pragma unroll
        for (int n = 0; n < 4; ++n) {
            int col = wc * 64 + n * 16 + (lane & 15);
            #pragma unroll
            for (int i = 0; i < 4; ++i) {
                int row = wr * 64 + m * 16 + (lane >> 4) * 4 + i;
                float v = acc[m][n][i];
                v = v > 0.f ? v * v : 0.f;
                sC[row * 128 + col] = f2bf(v);
            }
        }
    __syncthreads();
    #pragma unroll
    for (int it = 0; it < 8; ++it) {
        int idx = tid + it * 256;
        int row = idx >> 4, j = idx & 15;
        *(int4v*)&H[(size_t)(base + row) * DFF + nt * 128 + j * 8] =
            *(const int4v*)&sC[row * 128 + j * 8];
    }
}

// ---------------- GEMM2: obuf[slot] = H @ WpT^T, 64x128 tile, BK=64, XOR-swizzled LDS ----
__global__ __launch_bounds__(256) void k_gemm2(
    const unsigned short* __restrict__ H, const unsigned short* __restrict__ WpT,
    const int* __restrict__ ctrl, float* __restrict__ obuf)
{
    int bx = blockIdx.x;                      // grid = MAXT2*NT2 = 480
    int swz = (bx & 7) * (MAXT2 * NT2 / 8) + (bx >> 3);
    int nt = swz / MAXT2, tI = swz % MAXT2;
    if (tI >= ctrl[26]) return;
    int pk = ctrl[128 + tI];
    int e = pk >> 16, mt = pk & 0xffff;
    int base = ctrl[16 + e] + (mt << 6);

    __shared__ unsigned short sA[64 * 64];    // 8 KB
    __shared__ unsigned short sB[128 * 64];   // 16 KB

    int tid = threadIdx.x, w = tid >> 6, lane = tid & 63;
    int wr = w >> 1, wc = w & 1;

    int swsub = (((lane & 7) ^ ((lane >> 3) & 7)) << 3);
    const unsigned short* wp = WpT + ((size_t)e * NEMBD + nt * 128) * DFF;
    const unsigned short* aptr[2]; const unsigned short* bptr[4];
    #pragma unroll
    for (int i = 0; i < 2; ++i) {
        int r = i * 32 + w * 8 + (lane >> 3);
        aptr[i] = H + (size_t)(base + r) * DFF + swsub;
    }
    #pragma unroll
    for (int i = 0; i < 4; ++i) {
        int r = i * 32 + w * 8 + (lane >> 3);
        bptr[i] = wp + (size_t)r * DFF + swsub;
    }

    f32x4 acc[2][4];
    #pragma unroll
    for (int i = 0; i < 2; ++i)
        #pragma unroll
        for (int j = 0; j < 4; ++j) acc[i][j] = (f32x4){0.f, 0.f, 0.f, 0.f};

    int rsw = (lane & 7) << 3;
    for (int kk = 0; kk < DFF; kk += 64) {
        #pragma unroll
        for (int i = 0; i < 2; ++i)
            gload16(aptr[i] + kk, &sA[(i * 256 + w * 64) * 8]);
        #pragma unroll
        for (int i = 0; i < 4; ++i)
            gload16(bptr[i] + kk, &sB[(i * 256 + w * 64) * 8]);
        __syncthreads();
        #pragma unroll
        for (int kh = 0; kh < 2; ++kh) {
            int c = (kh * 32 + ((lane >> 4) << 3)) ^ rsw;
            short8v af[2], bfv[4];
            #pragma unroll
            for (int m = 0; m < 2; ++m)
                af[m] = *(const short8v*)&sA[(wr * 32 + m * 16 + (lane & 15)) * 64 + c];
            #pragma unroll
            for (int n = 0; n < 4; ++n)
                bfv[n] = *(const short8v*)&sB[(wc * 64 + n * 16 + (lane & 15)) * 64 + c];
            #pragma unroll
            for (int m = 0; m < 2; ++m)
                #pragma unroll
                for (int n = 0; n < 4; ++n)
                    acc[m][n] = __builtin_amdgcn_mfma_f32_16x16x32_bf16(af[m], bfv[n], acc[m][n], 0, 0, 0);
        }
        __syncthreads();
    }

    #pragma unroll
    for (int m = 0; m < 2; ++m)
        #pragma unroll
        for (int n = 0; n < 4; ++n) {
            int col = nt * 128 + wc * 64 + n * 16 + (lane & 15);
            #pragma unroll
            for (int i = 0; i < 4; ++i) {
                int row = wr * 32 + m * 16 + (lane >> 4) * 4 + i;
                obuf[(size_t)(base + row) * NEMBD + col] = acc[m][n][i];
            }
        }
}

// ---------------- finish: combine (blocks 0..511) + aux loss (block 512) ----------------
__global__ __launch_bounds__(256) void k_finish(
    const float* __restrict__ obuf, const int* __restrict__ tslot,
    const float* __restrict__ tw, const float* __restrict__ gates,
    const float* __restrict__ kl_tok, const int* __restrict__ ctrl,
    float* __restrict__ out)
{
    int tid = threadIdx.x;
    if (blockIdx.x == 512) {
        __shared__ float sred[256];
        float p[NEXP]; float kls = 0.f;
        #pragma unroll
        for (int e = 0; e < NEXP; ++e) p[e] = 0.f;
        for (int t = tid; t < NTOK; t += 256) {
            #pragma unroll
            for (int e = 0; e < NEXP; ++e) p[e] += gates[t * NEXP + e];
            kls += kl_tok[t];
        }
        float Ps[NEXP];
        for (int e = 0; e < NEXP; ++e) {
            sred[tid] = p[e]; __syncthreads();
            for (int s = 128; s; s >>= 1) { if (tid < s) sred[tid] += sred[tid + s]; __syncthreads(); }
            if (tid == 0) Ps[e] = sred[0];
            __syncthreads();
        }
        sred[tid] = kls; __syncthreads();
        for (int s = 128; s; s >>= 1) { if (tid < s) sred[tid] += sred[tid + s]; __syncthreads(); }
        if (tid == 0) {
            float kl_mean = sred[0] / (float)NTOK;
            float lb = 0.f;
            for (int e = 0; e < NEXP; ++e)
                lb += ((float)ctrl[e] / (float)(NTOK * 2)) * (Ps[e] / (float)NTOK);
            lb *= (float)NEXP * 0.01f;
            out[(size_t)NTOK * NEMBD] = lb + kl_mean;
        }
        return;
    }
    int wave = tid >> 6, lane = tid & 63;
    int t = blockIdx.x * 4 + wave;
    int s0 = tslot[t * 2], s1 = tslot[t * 2 + 1];
    float g0 = tw[t * 2], g1 = tw[t * 2 + 1];
    const float4* r0 = (const float4*)(obuf + (size_t)s0 * NEMBD);
    const float4* r1 = (const float4*)(obuf + (size_t)s1 * NEMBD);
    float4* o4 = (float4*)(out + (size_t)t * NEMBD);
    #pragma unroll
    for (int j = 0; j < 3; ++j) {
        int c = j * 64 + lane;
        float4 a = r0[c], b = r1[c];
        float4 o;
        o.x = g0 * a.x + g1 * b.x; o.y = g0 * a.y + g1 * b.y;
        o.z = g0 * a.z + g1 * b.z; o.w = g0 * a.w + g1 * b.w;
        o4[c] = o;
    }
}

extern "C" void kernel_launch(void* const* d_in, const int* in_sizes, int n_in,
                              void* d_out, int out_size, void* d_ws, size_t ws_size,
                              hipStream_t stream) {
    const float* x   = (const float*)d_in[0];
    const float* WgP = (const float*)d_in[1];
    const float* WgQ = (const float*)d_in[2];
    const float* Wfc = (const float*)d_in[3];
    const float* Wpj = (const float*)d_in[4];
    float* out = (float*)d_out;

    char* ws = (char*)d_ws;
    unsigned short* xbf  = (unsigned short*)(ws + WS_XBF);
    float* gates = (float*)(ws + WS_GATES);
    int*   te    = (int*)(ws + WS_TE);
    float* tw    = (float*)(ws + WS_TW);
    float* klt   = (float*)(ws + WS_KL);
    int*   ctrl  = (int*)(ws + WS_CTRL);
    int*   stok  = (int*)(ws + WS_STOK);
    int*   tslot = (int*)(ws + WS_TSLOT);
    unsigned short* WfcT = (unsigned short*)(ws + WS_WFCT);
    unsigned short* WpT  = (unsigned short*)(ws + WS_WPT);
    unsigned short* H    = (unsigned short*)(ws + WS_H);
    float* obuf  = (float*)(ws + WS_OBUF);   // aliases WfcT (dead after gemm1)

    k_front<<<512 + 2304 + 2304, 256, 0, stream>>>(
        x, WgP, WgQ, Wfc, Wpj, WfcT, WpT, xbf, gates, te, tw, klt);
    k_sched<<<1, 256, 0, stream>>>(te, ctrl, stok, tslot);
    k_gemm1<<<MAXT1 * NT1, 256, 0, stream>>>(xbf, WfcT, ctrl, stok, H);
    k_gemm2<<<MAXT2 * NT2, 256, 0, stream>>>(H, WpT, ctrl, obuf);
    k_finish<<<513, 256, 0, stream>>>(obuf, tslot, tw, gates, klt, ctrl, out);
}

// Round 15
// 162.944 us; speedup vs baseline: 1.0232x; 1.0232x over previous
//
#include <hip/hip_runtime.h>
#include <hip/hip_bf16.h>

typedef __attribute__((ext_vector_type(8))) short short8v;   // 8 bf16
typedef __attribute__((ext_vector_type(4))) short short4v;   // 4 bf16
typedef __attribute__((ext_vector_type(4))) float f32x4;
typedef __attribute__((ext_vector_type(4))) int int4v;

#define NTOK  2048
#define NEMBD 768
#define DFF   3072
#define NEXP  8
#define MAXSLOT 5120          // 128-aligned per-expert regions, sum <= 5120
#define NT1 24                // DFF/128
#define NT2 6                 // NEMBD/128
#define MAXT1 40              // max 128-row tiles
#define MAXT2 80              // max 64-row tiles

// ---- workspace layout (bytes) ----
#define WS_XBF   0                                   // ushort [2048][768]
#define WS_GATES (WS_XBF + (size_t)NTOK*NEMBD*2)     // float  [2048][8]
#define WS_TE    (WS_GATES + NTOK*8*4)               // int    [2048][2]
#define WS_TW    (WS_TE + NTOK*2*4)                  // float  [2048][2]
#define WS_KL    (WS_TW + NTOK*2*4)                  // float  [2048]
#define WS_CTRL  (WS_KL + NTOK*4)                    // int[512]
#define WS_STOK  (WS_CTRL + 2048)                    // int    [MAXSLOT]
#define WS_TSLOT (WS_STOK + MAXSLOT*4)               // int    [2048][2]
#define WS_WFCT  (WS_TSLOT + NTOK*2*4)               // ushort [8][3072][768]
#define WS_WPT   (WS_WFCT + (size_t)NEXP*DFF*NEMBD*2)// ushort [8][768][3072]
#define WS_H     (WS_WPT + (size_t)NEXP*NEMBD*DFF*2) // ushort [MAXSLOT][3072]
#define WS_OBUF  (WS_H + (size_t)MAXSLOT*DFF*2)      // ushort [MAXSLOT][768] bf16

__device__ __forceinline__ unsigned short f2bf(float f) {
    union { float f; unsigned u; } v; v.f = f;
    unsigned r = v.u + 0x7fffu + ((v.u >> 16) & 1u);   // RNE
    return (unsigned short)(r >> 16);
}

__device__ __forceinline__ float bf2f(unsigned short u) {
    union { unsigned u; float f; } v; v.u = ((unsigned)u) << 16;
    return v.f;
}

__device__ __forceinline__ void gload16(const void* g, void* l) {
    __builtin_amdgcn_global_load_lds(
        (const __attribute__((address_space(1))) void*)g,
        (__attribute__((address_space(3))) void*)l, 16, 0, 0);
}

// ---- transpose tile: in [E][R][C] f32 -> out [E][C][R] bf16 ----
// tile 128 k-rows x 64 n-cols; LDS [n=64][slot=32 of 4 bf16], row stride 264B (+8 pad),
// slot XOR (n>>3)&3. NT loads (ext-vector f32x4) on the single-use fp32 weight stream.
#define SROW 264
__device__ __forceinline__ void transpose_tile(
    const float* __restrict__ in, unsigned short* __restrict__ out,
    int R, int C, int tilesC, int tb, char* sT, int tid)
{
    int e = tb / 288, rem = tb % 288;
    int rt = rem / tilesC, ct = rem % tilesC;
    int ng = tid & 7, kg = tid >> 3;          // ng: n-octet (8), kg: k-quad (0..31)
    const float* src = in + ((size_t)e * R + rt * 128 + kg * 4) * C + ct * 64 + ng * 8;
    unsigned short cb[8][4];
    #pragma unroll
    for (int i = 0; i < 4; ++i) {
        f32x4 a = __builtin_nontemporal_load((const f32x4*)&src[(size_t)i * C]);
        f32x4 b = __builtin_nontemporal_load((const f32x4*)&src[(size_t)i * C + 4]);
        cb[0][i] = f2bf(a[0]); cb[1][i] = f2bf(a[1]); cb[2][i] = f2bf(a[2]); cb[3][i] = f2bf(a[3]);
        cb[4][i] = f2bf(b[0]); cb[5][i] = f2bf(b[1]); cb[6][i] = f2bf(b[2]); cb[7][i] = f2bf(b[3]);
    }
    #pragma unroll
    for (int j = 0; j < 8; ++j) {
        int n = ng * 8 + j;
        int sl = kg ^ ((n >> 3) & 3);         // bijective per n
        *(short4v*)(sT + n * SROW + sl * 8) = *(const short4v*)&cb[j][0];
    }
    __syncthreads();
    int n2 = tid >> 2, cs = tid & 3;          // n2: 0..63, cs: k-chunk (32 elems)
    unsigned short tmp[32];
    #pragma unroll
    for (int i = 0; i < 8; ++i) {
        int sl = (cs * 8 + i) ^ ((n2 >> 3) & 3);
        *(short4v*)&tmp[i * 4] = *(const short4v*)(sT + n2 * SROW + sl * 8);
    }
    unsigned short* dstp = out + ((size_t)e * C + ct * 64 + n2) * R + rt * 128 + cs * 32;
    #pragma unroll
    for (int q = 0; q < 4; ++q)
        *(int4v*)&dstp[q * 8] = *(const int4v*)&tmp[q * 8];
}

// ---------------- front: router (0..511) + Wfc T (512..2815) + Wp T (2816..5119) ----------
__global__ __launch_bounds__(256) void k_front(
    const float* __restrict__ x, const float* __restrict__ WgP, const float* __restrict__ WgQ,
    const float* __restrict__ Wfc, const float* __restrict__ Wpj,
    unsigned short* __restrict__ WfcT, unsigned short* __restrict__ WpT,
    unsigned short* __restrict__ xbf, float* __restrict__ gates,
    int* __restrict__ te, float* __restrict__ tw, float* __restrict__ kl_tok)
{
    __shared__ char sT[64 * SROW];   // 16.9 KB
    int tid = threadIdx.x;
    int bid = blockIdx.x;
    if (bid >= 2816) {
        transpose_tile(Wpj, WpT, DFF, NEMBD, 12, bid - 2816, sT, tid);
        return;
    }
    if (bid >= 512) {
        transpose_tile(Wfc, WfcT, NEMBD, DFF, 48, bid - 512, sT, tid);
        return;
    }
    // -------- router: one wave per token, no global atomics --------
    int rb = bid;   // 0..511
    int wave = tid >> 6, lane = tid & 63;
    int t = rb * 4 + wave;
    int b = t >> 10, l = t & 1023;
    int lf = l + 2; if (lf > 1023) lf = 1023;           // lookforward pad-with-last
    const float* xr = x + (size_t)t * NEMBD;
    const float* xf = x + (size_t)((b << 10) + lf) * NEMBD;
    int e = lane & 7, kg = lane >> 3;

    float accP = 0.f, accQ = 0.f;
    #pragma unroll 8
    for (int i = 0; i < 96; ++i) {
        int k = kg + 8 * i;
        accP += xr[k] * WgP[k * NEXP + e];
        accQ += xf[k] * WgQ[k * NEXP + e];
    }
    #pragma unroll
    for (int off = 8; off < 64; off <<= 1) {
        accP += __shfl_xor(accP, off);
        accQ += __shfl_xor(accQ, off);
    }
    float mq = accQ, mp = accP;
    #pragma unroll
    for (int off = 1; off < 8; off <<= 1) {
        mq = fmaxf(mq, __shfl_xor(mq, off));
        mp = fmaxf(mp, __shfl_xor(mp, off));
    }
    float gq = __expf(accQ - mq), gp = __expf(accP - mp);
    float se = gq, sp = gp;
    #pragma unroll
    for (int off = 1; off < 8; off <<= 1) {
        se += __shfl_xor(se, off);
        sp += __shfl_xor(sp, off);
    }
    float v0 = gq; int e0 = e;
    #pragma unroll
    for (int off = 1; off < 8; off <<= 1) {
        float ov = __shfl_xor(v0, off); int oe = __shfl_xor(e0, off);
        if (ov > v0 || (ov == v0 && oe < e0)) { v0 = ov; e0 = oe; }
    }
    float vx = (e == e0) ? -1.f : gq;
    float v1 = vx; int e1 = e;
    #pragma unroll
    for (int off = 1; off < 8; off <<= 1) {
        float ov = __shfl_xor(v1, off); int oe = __shfl_xor(e1, off);
        if (ov > v1 || (ov == v1 && oe < e1)) { v1 = ov; e1 = oe; }
    }
    float lq = (accQ - mq) - logf(se);
    float lp = (accP - mp) - logf(sp);
    float kl = __expf(lq) * (lq - lp);
    #pragma unroll
    for (int off = 1; off < 8; off <<= 1) kl += __shfl_xor(kl, off);

    if (lane < 8) gates[t * NEXP + e] = gq / se;
    if (lane == 0) {
        float s2 = v0 + v1;
        te[t * 2] = e0; te[t * 2 + 1] = e1;
        tw[t * 2] = v0 / s2; tw[t * 2 + 1] = v1 / s2;
        kl_tok[t] = kl;
    }
    // x -> bf16 for this block's 4 token rows
    const float4* xs4 = (const float4*)(x + (size_t)rb * 4 * NEMBD);
    ushort4* xd4 = (ushort4*)(xbf + (size_t)rb * 4 * NEMBD);
    for (int i = tid; i < 4 * NEMBD / 4; i += 256) {
        float4 v = xs4[i];
        ushort4 o;
        o.x = f2bf(v.x); o.y = f2bf(v.y); o.z = f2bf(v.z); o.w = f2bf(v.w);
        xd4[i] = o;
    }
}

// ---------------- sched: histogram + offsets + tile tables + slot lists (1 block) ---------
// ctrl: [0..7] counts, [16..23] expert base, [24] total, [25] nt1, [26] nt2,
//       [64..103] t1 (e<<16|mt), [128..207] t2
__global__ __launch_bounds__(256) void k_sched(
    const int* __restrict__ te, int* __restrict__ ctrl,
    int* __restrict__ stok, int* __restrict__ tslot)
{
    __shared__ int cur[NEXP];
    __shared__ int cnt_s[NEXP];
    __shared__ int sOff[NEXP];
    int tid = threadIdx.x, lane = tid & 63;
    if (tid < NEXP) { cur[tid] = 0; cnt_s[tid] = 0; }
    for (int i = tid; i < MAXSLOT; i += 256) stok[i] = 0;
    __syncthreads();
    int cc[NEXP];
    #pragma unroll
    for (int e = 0; e < NEXP; ++e) cc[e] = 0;
    for (int i = tid; i < NTOK * 2; i += 256) {
        int e = te[i];
        #pragma unroll
        for (int q = 0; q < NEXP; ++q) cc[q] += (e == q) ? 1 : 0;
    }
    #pragma unroll
    for (int e = 0; e < NEXP; ++e) {
        int v = cc[e];
        #pragma unroll
        for (int off = 32; off; off >>= 1) v += __shfl_xor(v, off);
        if (lane == 0) atomicAdd(&cnt_s[e], v);
    }
    __syncthreads();
    if (tid == 0) {
        int off = 0, n1 = 0, n2 = 0;
        for (int e = 0; e < NEXP; ++e) {
            int cnt = cnt_s[e];
            ctrl[e] = cnt;
            ctrl[16 + e] = off; sOff[e] = off;
            int t128 = (cnt + 127) >> 7;
            for (int m = 0; m < t128; ++m)     ctrl[64 + n1++]  = (e << 16) | m;
            for (int m = 0; m < 2 * t128; ++m) ctrl[128 + n2++] = (e << 16) | m;
            off += t128 << 7;
        }
        ctrl[24] = off; ctrl[25] = n1; ctrl[26] = n2;
    }
    __syncthreads();
    for (int t = tid; t < NTOK; t += 256) {
        #pragma unroll
        for (int k = 0; k < 2; ++k) {
            int e = te[t * 2 + k];
            int s = atomicAdd(&cur[e], 1);
            int flat = sOff[e] + s;
            stok[flat] = t; tslot[t * 2 + k] = flat;
        }
    }
}

// ---------------- GEMM1: H = relu(Xg @ WfcT^T)^2, 128x128 tile, BK=64, XOR-swizzled LDS ----
__global__ __launch_bounds__(256) void k_gemm1(
    const unsigned short* __restrict__ xbf, const unsigned short* __restrict__ WfcT,
    const int* __restrict__ ctrl, const int* __restrict__ slot_tok,
    unsigned short* __restrict__ H)
{
    int bx = blockIdx.x;                      // grid = MAXT1*NT1 = 960
    int swz = (bx & 7) * (MAXT1 * NT1 / 8) + (bx >> 3);
    int nt = swz / MAXT1, tI = swz % MAXT1;
    if (tI >= ctrl[25]) return;
    int pk = ctrl[64 + tI];
    int e = pk >> 16, mt = pk & 0xffff;
    int base = ctrl[16 + e] + (mt << 7);

    __shared__ unsigned short sAB[2 * 128 * 64];   // sA | sB, reused as sC[128][128]
    unsigned short* sA = sAB;
    unsigned short* sB = sAB + 128 * 64;

    int tid = threadIdx.x, w = tid >> 6, lane = tid & 63;
    int wr = w >> 1, wc = w & 1;

    int swsub = (((lane & 7) ^ ((lane >> 3) & 7)) << 3);
    const unsigned short* wfc = WfcT + ((size_t)e * DFF + nt * 128) * NEMBD;
    const unsigned short* aptr[4]; const unsigned short* bptr[4];
    #pragma unroll
    for (int i = 0; i < 4; ++i) {
        int r = i * 32 + w * 8 + (lane >> 3);
        aptr[i] = xbf + (size_t)slot_tok[base + r] * NEMBD + swsub;
        bptr[i] = wfc + (size_t)r * NEMBD + swsub;
    }

    f32x4 acc[4][4];
    #pragma unroll
    for (int i = 0; i < 4; ++i)
        #pragma unroll
        for (int j = 0; j < 4; ++j) acc[i][j] = (f32x4){0.f, 0.f, 0.f, 0.f};

    int rsw = (lane & 7) << 3;
    for (int kk = 0; kk < NEMBD; kk += 64) {
        #pragma unroll
        for (int i = 0; i < 4; ++i) {
            gload16(aptr[i] + kk, &sA[(i * 256 + w * 64) * 8]);
            gload16(bptr[i] + kk, &sB[(i * 256 + w * 64) * 8]);
        }
        __syncthreads();
        #pragma unroll
        for (int kh = 0; kh < 2; ++kh) {
            int c = (kh * 32 + ((lane >> 4) << 3)) ^ rsw;
            short8v af[4], bfv[4];
            #pragma unroll
            for (int m = 0; m < 4; ++m)
                af[m] = *(const short8v*)&sA[(wr * 64 + m * 16 + (lane & 15)) * 64 + c];
            #pragma unroll
            for (int n = 0; n < 4; ++n)
                bfv[n] = *(const short8v*)&sB[(wc * 64 + n * 16 + (lane & 15)) * 64 + c];
            #pragma unroll
            for (int m = 0; m < 4; ++m)
                #pragma unroll
                for (int n = 0; n < 4; ++n)
                    acc[m][n] = __builtin_amdgcn_mfma_f32_16x16x32_bf16(af[m], bfv[n], acc[m][n], 0, 0, 0);
        }
        __syncthreads();
    }

    unsigned short* sC = sAB;   // [128][128]
    #pragma unroll
    for (int m = 0; m < 4; ++m)
        #pragma unroll
        for (int n = 0; n < 4; ++n) {
            int col = wc * 64 + n * 16 + (lane & 15);
            #pragma unroll
            for (int i = 0; i < 4; ++i) {
                int row = wr * 64 + m * 16 + (lane >> 4) * 4 + i;
                float v = acc[m][n][i];
                v = v > 0.f ? v * v : 0.f;
                sC[row * 128 + col] = f2bf(v);
            }
        }
    __syncthreads();
    #pragma unroll
    for (int it = 0; it < 8; ++it) {
        int idx = tid + it * 256;
        int row = idx >> 4, j = idx & 15;
        *(int4v*)&H[(size_t)(base + row) * DFF + nt * 128 + j * 8] =
            *(const int4v*)&sC[row * 128 + j * 8];
    }
}

// ---------------- GEMM2: obuf[slot] = H @ WpT^T (bf16 out), 64x128 tile, BK=64 ----------
__global__ __launch_bounds__(256) void k_gemm2(
    const unsigned short* __restrict__ H, const unsigned short* __restrict__ WpT,
    const int* __restrict__ ctrl, unsigned short* __restrict__ obuf)
{
    int bx = blockIdx.x;                      // grid = MAXT2*NT2 = 480
    int swz = (bx & 7) * (MAXT2 * NT2 / 8) + (bx >> 3);
    int nt = swz / MAXT2, tI = swz % MAXT2;
    if (tI >= ctrl[26]) return;
    int pk = ctrl[128 + tI];
    int e = pk >> 16, mt = pk & 0xffff;
    int base = ctrl[16 + e] + (mt << 6);

    __shared__ unsigned short sA[64 * 64];    // 8 KB
    __shared__ unsigned short sB[128 * 64];   // 16 KB

    int tid = threadIdx.x, w = tid >> 6, lane = tid & 63;
    int wr = w >> 1, wc = w & 1;

    int swsub = (((lane & 7) ^ ((lane >> 3) & 7)) << 3);
    const unsigned short* wp = WpT + ((size_t)e * NEMBD + nt * 128) * DFF;
    const unsigned short* aptr[2]; const unsigned short* bptr[4];
    #pragma unroll
    for (int i = 0; i < 2; ++i) {
        int r = i * 32 + w * 8 + (lane >> 3);
        aptr[i] = H + (size_t)(base + r) * DFF + swsub;
    }
    #pragma unroll
    for (int i = 0; i < 4; ++i) {
        int r = i * 32 + w * 8 + (lane >> 3);
        bptr[i] = wp + (size_t)r * DFF + swsub;
    }

    f32x4 acc[2][4];
    #pragma unroll
    for (int i = 0; i < 2; ++i)
        #pragma unroll
        for (int j = 0; j < 4; ++j) acc[i][j] = (f32x4){0.f, 0.f, 0.f, 0.f};

    int rsw = (lane & 7) << 3;
    for (int kk = 0; kk < DFF; kk += 64) {
        #pragma unroll
        for (int i = 0; i < 2; ++i)
            gload16(aptr[i] + kk, &sA[(i * 256 + w * 64) * 8]);
        #pragma unroll
        for (int i = 0; i < 4; ++i)
            gload16(bptr[i] + kk, &sB[(i * 256 + w * 64) * 8]);
        __syncthreads();
        #pragma unroll
        for (int kh = 0; kh < 2; ++kh) {
            int c = (kh * 32 + ((lane >> 4) << 3)) ^ rsw;
            short8v af[2], bfv[4];
            #pragma unroll
            for (int m = 0; m < 2; ++m)
                af[m] = *(const short8v*)&sA[(wr * 32 + m * 16 + (lane & 15)) * 64 + c];
            #pragma unroll
            for (int n = 0; n < 4; ++n)
                bfv[n] = *(const short8v*)&sB[(wc * 64 + n * 16 + (lane & 15)) * 64 + c];
            #pragma unroll
            for (int m = 0; m < 2; ++m)
                #pragma unroll
                for (int n = 0; n < 4; ++n)
                    acc[m][n] = __builtin_amdgcn_mfma_f32_16x16x32_bf16(af[m], bfv[n], acc[m][n], 0, 0, 0);
        }
        __syncthreads();
    }

    #pragma unroll
    for (int m = 0; m < 2; ++m)
        #pragma unroll
        for (int n = 0; n < 4; ++n) {
            int col = nt * 128 + wc * 64 + n * 16 + (lane & 15);
            #pragma unroll
            for (int i = 0; i < 4; ++i) {
                int row = wr * 32 + m * 16 + (lane >> 4) * 4 + i;
                obuf[(size_t)(base + row) * NEMBD + col] = f2bf(acc[m][n][i]);
            }
        }
}

// ---------------- finish: combine (blocks 0..511) + aux loss (block 512) ----------------
__global__ __launch_bounds__(256) void k_finish(
    const unsigned short* __restrict__ obuf, const int* __restrict__ tslot,
    const float* __restrict__ tw, const float* __restrict__ gates,
    const float* __restrict__ kl_tok, const int* __restrict__ ctrl,
    float* __restrict__ out)
{
    int tid = threadIdx.x;
    if (blockIdx.x == 512) {
        __shared__ float sred[256];
        float p[NEXP]; float kls = 0.f;
        #pragma unroll
        for (int e = 0; e < NEXP; ++e) p[e] = 0.f;
        for (int t = tid; t < NTOK; t += 256) {
            #pragma unroll
            for (int e = 0; e < NEXP; ++e) p[e] += gates[t * NEXP + e];
            kls += kl_tok[t];
        }
        float Ps[NEXP];
        for (int e = 0; e < NEXP; ++e) {
            sred[tid] = p[e]; __syncthreads();
            for (int s = 128; s; s >>= 1) { if (tid < s) sred[tid] += sred[tid + s]; __syncthreads(); }
            if (tid == 0) Ps[e] = sred[0];
            __syncthreads();
        }
        sred[tid] = kls; __syncthreads();
        for (int s = 128; s; s >>= 1) { if (tid < s) sred[tid] += sred[tid + s]; __syncthreads(); }
        if (tid == 0) {
            float kl_mean = sred[0] / (float)NTOK;
            float lb = 0.f;
            for (int e = 0; e < NEXP; ++e)
                lb += ((float)ctrl[e] / (float)(NTOK * 2)) * (Ps[e] / (float)NTOK);
            lb *= (float)NEXP * 0.01f;
            out[(size_t)NTOK * NEMBD] = lb + kl_mean;
        }
        return;
    }
    int wave = tid >> 6, lane = tid & 63;
    int t = blockIdx.x * 4 + wave;
    int s0 = tslot[t * 2], s1 = tslot[t * 2 + 1];
    float g0 = tw[t * 2], g1 = tw[t * 2 + 1];
    const ushort4* r0 = (const ushort4*)(obuf + (size_t)s0 * NEMBD);
    const ushort4* r1 = (const ushort4*)(obuf + (size_t)s1 * NEMBD);
    float4* o4 = (float4*)(out + (size_t)t * NEMBD);
    #pragma unroll
    for (int j = 0; j < 3; ++j) {
        int c = j * 64 + lane;
        ushort4 a = r0[c], b = r1[c];
        float4 o;
        o.x = g0 * bf2f(a.x) + g1 * bf2f(b.x);
        o.y = g0 * bf2f(a.y) + g1 * bf2f(b.y);
        o.z = g0 * bf2f(a.z) + g1 * bf2f(b.z);
        o.w = g0 * bf2f(a.w) + g1 * bf2f(b.w);
        o4[c] = o;
    }
}

extern "C" void kernel_launch(void* const* d_in, const int* in_sizes, int n_in,
                              void* d_out, int out_size, void* d_ws, size_t ws_size,
                              hipStream_t stream) {
    const float* x   = (const float*)d_in[0];
    const float* WgP = (const float*)d_in[1];
    const float* WgQ = (const float*)d_in[2];
    const float* Wfc = (const float*)d_in[3];
    const float* Wpj = (const float*)d_in[4];
    float* out = (float*)d_out;

    char* ws = (char*)d_ws;
    unsigned short* xbf  = (unsigned short*)(ws + WS_XBF);
    float* gates = (float*)(ws + WS_GATES);
    int*   te    = (int*)(ws + WS_TE);
    float* tw    = (float*)(ws + WS_TW);
    float* klt   = (float*)(ws + WS_KL);
    int*   ctrl  = (int*)(ws + WS_CTRL);
    int*   stok  = (int*)(ws + WS_STOK);
    int*   tslot = (int*)(ws + WS_TSLOT);
    unsigned short* WfcT = (unsigned short*)(ws + WS_WFCT);
    unsigned short* WpT  = (unsigned short*)(ws + WS_WPT);
    unsigned short* H    = (unsigned short*)(ws + WS_H);
    unsigned short* obuf = (unsigned short*)(ws + WS_OBUF);

    k_front<<<512 + 2304 + 2304, 256, 0, stream>>>(
        x, WgP, WgQ, Wfc, Wpj, WfcT, WpT, xbf, gates, te, tw, klt);
    k_sched<<<1, 256, 0, stream>>>(te, ctrl, stok, tslot);
    k_gemm1<<<MAXT1 * NT1, 256, 0, stream>>>(xbf, WfcT, ctrl, stok, H);
    k_gemm2<<<MAXT2 * NT2, 256, 0, stream>>>(H, WpT, ctrl, obuf);
    k_finish<<<513, 256, 0, stream>>>(obuf, tslot, tw, gates, klt, ctrl, out);
}

// Round 16
// 151.341 us; speedup vs baseline: 1.1017x; 1.0767x over previous
//
#include <hip/hip_runtime.h>
#include <hip/hip_bf16.h>

typedef __attribute__((ext_vector_type(8))) short short8v;   // 8 bf16
typedef __attribute__((ext_vector_type(4))) short short4v;   // 4 bf16
typedef __attribute__((ext_vector_type(4))) float f32x4;
typedef __attribute__((ext_vector_type(4))) int int4v;

#define NTOK  2048
#define NEMBD 768
#define DFF   3072
#define NEXP  8
#define MAXSLOT 5120          // 128-aligned per-expert regions, sum <= 5120
#define NT1 24                // DFF/128
#define NT2 6                 // NEMBD/128
#define MAXT1 40              // max 128-row tiles
#define MAXT2 80              // max 64-row tiles

// ---- workspace layout (bytes) ----
#define WS_XBF   0                                   // ushort [2048][768]
#define WS_GATES (WS_XBF + (size_t)NTOK*NEMBD*2)     // float  [2048][8]
#define WS_TE    (WS_GATES + NTOK*8*4)               // int    [2048][2]
#define WS_TW    (WS_TE + NTOK*2*4)                  // float  [2048][2]
#define WS_KL    (WS_TW + NTOK*2*4)                  // float  [2048]
#define WS_CTRL  (WS_KL + NTOK*4)                    // int[512]
#define WS_STOK  (WS_CTRL + 2048)                    // int    [MAXSLOT]
#define WS_TSLOT (WS_STOK + MAXSLOT*4)               // int    [2048][2]
#define WS_WFCT  (WS_TSLOT + NTOK*2*4)               // ushort [8][3072][768]
#define WS_WPT   (WS_WFCT + (size_t)NEXP*DFF*NEMBD*2)// ushort [8][768][3072]
#define WS_H     (WS_WPT + (size_t)NEXP*NEMBD*DFF*2) // ushort [MAXSLOT][3072]
#define WS_OBUF  (WS_H + (size_t)MAXSLOT*DFF*2)      // ushort [MAXSLOT][768] bf16

__device__ __forceinline__ unsigned short f2bf(float f) {
    union { float f; unsigned u; } v; v.f = f;
    unsigned r = v.u + 0x7fffu + ((v.u >> 16) & 1u);   // RNE
    return (unsigned short)(r >> 16);
}

__device__ __forceinline__ float bf2f(unsigned short u) {
    union { unsigned u; float f; } v; v.u = ((unsigned)u) << 16;
    return v.f;
}

__device__ __forceinline__ void gload16(const void* g, void* l) {
    __builtin_amdgcn_global_load_lds(
        (const __attribute__((address_space(1))) void*)g,
        (__attribute__((address_space(3))) void*)l, 16, 0, 0);
}

// ---- transpose tile: in [E][R][C] f32 -> out [E][C][R] bf16 ----
// tile 128 k-rows x 64 n-cols; LDS [n=64][slot=32 of 4 bf16], row stride 264B (+8 pad),
// slot XOR (n>>3)&3. Plain loads (NT reverted: A/B showed NT shifts cost downstream).
#define SROW 264
__device__ __forceinline__ void transpose_tile(
    const float* __restrict__ in, unsigned short* __restrict__ out,
    int R, int C, int tilesC, int tb, char* sT, int tid)
{
    int e = tb / 288, rem = tb % 288;
    int rt = rem / tilesC, ct = rem % tilesC;
    int ng = tid & 7, kg = tid >> 3;          // ng: n-octet (8), kg: k-quad (0..31)
    const float* src = in + ((size_t)e * R + rt * 128 + kg * 4) * C + ct * 64 + ng * 8;
    unsigned short cb[8][4];
    #pragma unroll
    for (int i = 0; i < 4; ++i) {
        f32x4 a = *(const f32x4*)&src[(size_t)i * C];
        f32x4 b = *(const f32x4*)&src[(size_t)i * C + 4];
        cb[0][i] = f2bf(a[0]); cb[1][i] = f2bf(a[1]); cb[2][i] = f2bf(a[2]); cb[3][i] = f2bf(a[3]);
        cb[4][i] = f2bf(b[0]); cb[5][i] = f2bf(b[1]); cb[6][i] = f2bf(b[2]); cb[7][i] = f2bf(b[3]);
    }
    #pragma unroll
    for (int j = 0; j < 8; ++j) {
        int n = ng * 8 + j;
        int sl = kg ^ ((n >> 3) & 3);         // bijective per n
        *(short4v*)(sT + n * SROW + sl * 8) = *(const short4v*)&cb[j][0];
    }
    __syncthreads();
    int n2 = tid >> 2, cs = tid & 3;          // n2: 0..63, cs: k-chunk (32 elems)
    unsigned short tmp[32];
    #pragma unroll
    for (int i = 0; i < 8; ++i) {
        int sl = (cs * 8 + i) ^ ((n2 >> 3) & 3);
        *(short4v*)&tmp[i * 4] = *(const short4v*)(sT + n2 * SROW + sl * 8);
    }
    unsigned short* dstp = out + ((size_t)e * C + ct * 64 + n2) * R + rt * 128 + cs * 32;
    #pragma unroll
    for (int q = 0; q < 4; ++q)
        *(int4v*)&dstp[q * 8] = *(const int4v*)&tmp[q * 8];
}

// ---------------- front: router (0..511) + Wfc T (512..2815) + Wp T (2816..5119) ----------
__global__ __launch_bounds__(256) void k_front(
    const float* __restrict__ x, const float* __restrict__ WgP, const float* __restrict__ WgQ,
    const float* __restrict__ Wfc, const float* __restrict__ Wpj,
    unsigned short* __restrict__ WfcT, unsigned short* __restrict__ WpT,
    unsigned short* __restrict__ xbf, float* __restrict__ gates,
    int* __restrict__ te, float* __restrict__ tw, float* __restrict__ kl_tok)
{
    __shared__ char sT[64 * SROW];   // 16.9 KB
    int tid = threadIdx.x;
    int bid = blockIdx.x;
    if (bid >= 2816) {
        transpose_tile(Wpj, WpT, DFF, NEMBD, 12, bid - 2816, sT, tid);
        return;
    }
    if (bid >= 512) {
        transpose_tile(Wfc, WfcT, NEMBD, DFF, 48, bid - 512, sT, tid);
        return;
    }
    // -------- router: one wave per token, no global atomics --------
    int rb = bid;   // 0..511
    int wave = tid >> 6, lane = tid & 63;
    int t = rb * 4 + wave;
    int b = t >> 10, l = t & 1023;
    int lf = l + 2; if (lf > 1023) lf = 1023;           // lookforward pad-with-last
    const float* xr = x + (size_t)t * NEMBD;
    const float* xf = x + (size_t)((b << 10) + lf) * NEMBD;
    int e = lane & 7, kg = lane >> 3;

    float accP = 0.f, accQ = 0.f;
    #pragma unroll 8
    for (int i = 0; i < 96; ++i) {
        int k = kg + 8 * i;
        accP += xr[k] * WgP[k * NEXP + e];
        accQ += xf[k] * WgQ[k * NEXP + e];
    }
    #pragma unroll
    for (int off = 8; off < 64; off <<= 1) {
        accP += __shfl_xor(accP, off);
        accQ += __shfl_xor(accQ, off);
    }
    float mq = accQ, mp = accP;
    #pragma unroll
    for (int off = 1; off < 8; off <<= 1) {
        mq = fmaxf(mq, __shfl_xor(mq, off));
        mp = fmaxf(mp, __shfl_xor(mp, off));
    }
    float gq = __expf(accQ - mq), gp = __expf(accP - mp);
    float se = gq, sp = gp;
    #pragma unroll
    for (int off = 1; off < 8; off <<= 1) {
        se += __shfl_xor(se, off);
        sp += __shfl_xor(sp, off);
    }
    float v0 = gq; int e0 = e;
    #pragma unroll
    for (int off = 1; off < 8; off <<= 1) {
        float ov = __shfl_xor(v0, off); int oe = __shfl_xor(e0, off);
        if (ov > v0 || (ov == v0 && oe < e0)) { v0 = ov; e0 = oe; }
    }
    float vx = (e == e0) ? -1.f : gq;
    float v1 = vx; int e1 = e;
    #pragma unroll
    for (int off = 1; off < 8; off <<= 1) {
        float ov = __shfl_xor(v1, off); int oe = __shfl_xor(e1, off);
        if (ov > v1 || (ov == v1 && oe < e1)) { v1 = ov; e1 = oe; }
    }
    float lq = (accQ - mq) - logf(se);
    float lp = (accP - mp) - logf(sp);
    float kl = __expf(lq) * (lq - lp);
    #pragma unroll
    for (int off = 1; off < 8; off <<= 1) kl += __shfl_xor(kl, off);

    if (lane < 8) gates[t * NEXP + e] = gq / se;
    if (lane == 0) {
        float s2 = v0 + v1;
        te[t * 2] = e0; te[t * 2 + 1] = e1;
        tw[t * 2] = v0 / s2; tw[t * 2 + 1] = v1 / s2;
        kl_tok[t] = kl;
    }
    // x -> bf16 for this block's 4 token rows
    const float4* xs4 = (const float4*)(x + (size_t)rb * 4 * NEMBD);
    ushort4* xd4 = (ushort4*)(xbf + (size_t)rb * 4 * NEMBD);
    for (int i = tid; i < 4 * NEMBD / 4; i += 256) {
        float4 v = xs4[i];
        ushort4 o;
        o.x = f2bf(v.x); o.y = f2bf(v.y); o.z = f2bf(v.z); o.w = f2bf(v.w);
        xd4[i] = o;
    }
}

// ---------------- sched: histogram + offsets + tile tables + slot lists (1 block) ---------
// ctrl: [0..7] counts, [16..23] expert base, [24] total, [25] nt1, [26] nt2,
//       [64..103] t1 (e<<16|mt), [128..207] t2
__global__ __launch_bounds__(256) void k_sched(
    const int* __restrict__ te, int* __restrict__ ctrl,
    int* __restrict__ stok, int* __restrict__ tslot)
{
    __shared__ int cur[NEXP];
    __shared__ int cnt_s[NEXP];
    __shared__ int sOff[NEXP];
    int tid = threadIdx.x, lane = tid & 63;
    if (tid < NEXP) { cur[tid] = 0; cnt_s[tid] = 0; }
    for (int i = tid; i < MAXSLOT; i += 256) stok[i] = 0;
    __syncthreads();
    int cc[NEXP];
    #pragma unroll
    for (int e = 0; e < NEXP; ++e) cc[e] = 0;
    for (int i = tid; i < NTOK * 2; i += 256) {
        int e = te[i];
        #pragma unroll
        for (int q = 0; q < NEXP; ++q) cc[q] += (e == q) ? 1 : 0;
    }
    #pragma unroll
    for (int e = 0; e < NEXP; ++e) {
        int v = cc[e];
        #pragma unroll
        for (int off = 32; off; off >>= 1) v += __shfl_xor(v, off);
        if (lane == 0) atomicAdd(&cnt_s[e], v);
    }
    __syncthreads();
    if (tid == 0) {
        int off = 0, n1 = 0, n2 = 0;
        for (int e = 0; e < NEXP; ++e) {
            int cnt = cnt_s[e];
            ctrl[e] = cnt;
            ctrl[16 + e] = off; sOff[e] = off;
            int t128 = (cnt + 127) >> 7;
            for (int m = 0; m < t128; ++m)     ctrl[64 + n1++]  = (e << 16) | m;
            for (int m = 0; m < 2 * t128; ++m) ctrl[128 + n2++] = (e << 16) | m;
            off += t128 << 7;
        }
        ctrl[24] = off; ctrl[25] = n1; ctrl[26] = n2;
    }
    __syncthreads();
    for (int t = tid; t < NTOK; t += 256) {
        #pragma unroll
        for (int k = 0; k < 2; ++k) {
            int e = te[t * 2 + k];
            int s = atomicAdd(&cur[e], 1);
            int flat = sOff[e] + s;
            stok[flat] = t; tslot[t * 2 + k] = flat;
        }
    }
}

// ---------------- GEMM1: H = relu(Xg @ WfcT^T)^2, 128x128 tile, BK=64, XOR-swizzled LDS ----
__global__ __launch_bounds__(256) void k_gemm1(
    const unsigned short* __restrict__ xbf, const unsigned short* __restrict__ WfcT,
    const int* __restrict__ ctrl, const int* __restrict__ slot_tok,
    unsigned short* __restrict__ H)
{
    int bx = blockIdx.x;                      // grid = MAXT1*NT1 = 960
    int swz = (bx & 7) * (MAXT1 * NT1 / 8) + (bx >> 3);
    int nt = swz / MAXT1, tI = swz % MAXT1;
    if (tI >= ctrl[25]) return;
    int pk = ctrl[64 + tI];
    int e = pk >> 16, mt = pk & 0xffff;
    int base = ctrl[16 + e] + (mt << 7);

    __shared__ unsigned short sAB[2 * 128 * 64];   // sA | sB, reused as sC[128][128]
    unsigned short* sA = sAB;
    unsigned short* sB = sAB + 128 * 64;

    int tid = threadIdx.x, w = tid >> 6, lane = tid & 63;
    int wr = w >> 1, wc = w & 1;

    int swsub = (((lane & 7) ^ ((lane >> 3) & 7)) << 3);
    const unsigned short* wfc = WfcT + ((size_t)e * DFF + nt * 128) * NEMBD;
    const unsigned short* aptr[4]; const unsigned short* bptr[4];
    #pragma unroll
    for (int i = 0; i < 4; ++i) {
        int r = i * 32 + w * 8 + (lane >> 3);
        aptr[i] = xbf + (size_t)slot_tok[base + r] * NEMBD + swsub;
        bptr[i] = wfc + (size_t)r * NEMBD + swsub;
    }

    f32x4 acc[4][4];
    #pragma unroll
    for (int i = 0; i < 4; ++i)
        #pragma unroll
        for (int j = 0; j < 4; ++j) acc[i][j] = (f32x4){0.f, 0.f, 0.f, 0.f};

    int rsw = (lane & 7) << 3;
    for (int kk = 0; kk < NEMBD; kk += 64) {
        #pragma unroll
        for (int i = 0; i < 4; ++i) {
            gload16(aptr[i] + kk, &sA[(i * 256 + w * 64) * 8]);
            gload16(bptr[i] + kk, &sB[(i * 256 + w * 64) * 8]);
        }
        __syncthreads();
        #pragma unroll
        for (int kh = 0; kh < 2; ++kh) {
            int c = (kh * 32 + ((lane >> 4) << 3)) ^ rsw;
            short8v af[4], bfv[4];
            #pragma unroll
            for (int m = 0; m < 4; ++m)
                af[m] = *(const short8v*)&sA[(wr * 64 + m * 16 + (lane & 15)) * 64 + c];
            #pragma unroll
            for (int n = 0; n < 4; ++n)
                bfv[n] = *(const short8v*)&sB[(wc * 64 + n * 16 + (lane & 15)) * 64 + c];
            #pragma unroll
            for (int m = 0; m < 4; ++m)
                #pragma unroll
                for (int n = 0; n < 4; ++n)
                    acc[m][n] = __builtin_amdgcn_mfma_f32_16x16x32_bf16(af[m], bfv[n], acc[m][n], 0, 0, 0);
        }
        __syncthreads();
    }

    unsigned short* sC = sAB;   // [128][128]
    #pragma unroll
    for (int m = 0; m < 4; ++m)
        #pragma unroll
        for (int n = 0; n < 4; ++n) {
            int col = wc * 64 + n * 16 + (lane & 15);
            #pragma unroll
            for (int i = 0; i < 4; ++i) {
                int row = wr * 64 + m * 16 + (lane >> 4) * 4 + i;
                float v = acc[m][n][i];
                v = v > 0.f ? v * v : 0.f;
                sC[row * 128 + col] = f2bf(v);
            }
        }
    __syncthreads();
    #pragma unroll
    for (int it = 0; it < 8; ++it) {
        int idx = tid + it * 256;
        int row = idx >> 4, j = idx & 15;
        *(int4v*)&H[(size_t)(base + row) * DFF + nt * 128 + j * 8] =
            *(const int4v*)&sC[row * 128 + j * 8];
    }
}

// ---------------- GEMM2: obuf[slot] = H @ WpT^T (bf16 out), 64x128 tile, BK=64 ----------
__global__ __launch_bounds__(256) void k_gemm2(
    const unsigned short* __restrict__ H, const unsigned short* __restrict__ WpT,
    const int* __restrict__ ctrl, unsigned short* __restrict__ obuf)
{
    int bx = blockIdx.x;                      // grid = MAXT2*NT2 = 480
    int swz = (bx & 7) * (MAXT2 * NT2 / 8) + (bx >> 3);
    int nt = swz / MAXT2, tI = swz % MAXT2;
    if (tI >= ctrl[26]) return;
    int pk = ctrl[128 + tI];
    int e = pk >> 16, mt = pk & 0xffff;
    int base = ctrl[16 + e] + (mt << 6);

    __shared__ unsigned short sA[64 * 64];    // 8 KB
    __shared__ unsigned short sB[128 * 64];   // 16 KB

    int tid = threadIdx.x, w = tid >> 6, lane = tid & 63;
    int wr = w >> 1, wc = w & 1;

    int swsub = (((lane & 7) ^ ((lane >> 3) & 7)) << 3);
    const unsigned short* wp = WpT + ((size_t)e * NEMBD + nt * 128) * DFF;
    const unsigned short* aptr[2]; const unsigned short* bptr[4];
    #pragma unroll
    for (int i = 0; i < 2; ++i) {
        int r = i * 32 + w * 8 + (lane >> 3);
        aptr[i] = H + (size_t)(base + r) * DFF + swsub;
    }
    #pragma unroll
    for (int i = 0; i < 4; ++i) {
        int r = i * 32 + w * 8 + (lane >> 3);
        bptr[i] = wp + (size_t)r * DFF + swsub;
    }

    f32x4 acc[2][4];
    #pragma unroll
    for (int i = 0; i < 2; ++i)
        #pragma unroll
        for (int j = 0; j < 4; ++j) acc[i][j] = (f32x4){0.f, 0.f, 0.f, 0.f};

    int rsw = (lane & 7) << 3;
    for (int kk = 0; kk < DFF; kk += 64) {
        #pragma unroll
        for (int i = 0; i < 2; ++i)
            gload16(aptr[i] + kk, &sA[(i * 256 + w * 64) * 8]);
        #pragma unroll
        for (int i = 0; i < 4; ++i)
            gload16(bptr[i] + kk, &sB[(i * 256 + w * 64) * 8]);
        __syncthreads();
        #pragma unroll
        for (int kh = 0; kh < 2; ++kh) {
            int c = (kh * 32 + ((lane >> 4) << 3)) ^ rsw;
            short8v af[2], bfv[4];
            #pragma unroll
            for (int m = 0; m < 2; ++m)
                af[m] = *(const short8v*)&sA[(wr * 32 + m * 16 + (lane & 15)) * 64 + c];
            #pragma unroll
            for (int n = 0; n < 4; ++n)
                bfv[n] = *(const short8v*)&sB[(wc * 64 + n * 16 + (lane & 15)) * 64 + c];
            #pragma unroll
            for (int m = 0; m < 2; ++m)
                #pragma unroll
                for (int n = 0; n < 4; ++n)
                    acc[m][n] = __builtin_amdgcn_mfma_f32_16x16x32_bf16(af[m], bfv[n], acc[m][n], 0, 0, 0);
        }
        __syncthreads();
    }

    #pragma unroll
    for (int m = 0; m < 2; ++m)
        #pragma unroll
        for (int n = 0; n < 4; ++n) {
            int col = nt * 128 + wc * 64 + n * 16 + (lane & 15);
            #pragma unroll
            for (int i = 0; i < 4; ++i) {
                int row = wr * 32 + m * 16 + (lane >> 4) * 4 + i;
                obuf[(size_t)(base + row) * NEMBD + col] = f2bf(acc[m][n][i]);
            }
        }
}

// ---------------- finish: combine (blocks 0..511) + aux loss (block 512) ----------------
__global__ __launch_bounds__(256) void k_finish(
    const unsigned short* __restrict__ obuf, const int* __restrict__ tslot,
    const float* __restrict__ tw, const float* __restrict__ gates,
    const float* __restrict__ kl_tok, const int* __restrict__ ctrl,
    float* __restrict__ out)
{
    int tid = threadIdx.x;
    if (blockIdx.x == 512) {
        __shared__ float sred[256];
        float p[NEXP]; float kls = 0.f;
        #pragma unroll
        for (int e = 0; e < NEXP; ++e) p[e] = 0.f;
        for (int t = tid; t < NTOK; t += 256) {
            #pragma unroll
            for (int e = 0; e < NEXP; ++e) p[e] += gates[t * NEXP + e];
            kls += kl_tok[t];
        }
        float Ps[NEXP];
        for (int e = 0; e < NEXP; ++e) {
            sred[tid] = p[e]; __syncthreads();
            for (int s = 128; s; s >>= 1) { if (tid < s) sred[tid] += sred[tid + s]; __syncthreads(); }
            if (tid == 0) Ps[e] = sred[0];
            __syncthreads();
        }
        sred[tid] = kls; __syncthreads();
        for (int s = 128; s; s >>= 1) { if (tid < s) sred[tid] += sred[tid + s]; __syncthreads(); }
        if (tid == 0) {
            float kl_mean = sred[0] / (float)NTOK;
            float lb = 0.f;
            for (int e = 0; e < NEXP; ++e)
                lb += ((float)ctrl[e] / (float)(NTOK * 2)) * (Ps[e] / (float)NTOK);
            lb *= (float)NEXP * 0.01f;
            out[(size_t)NTOK * NEMBD] = lb + kl_mean;
        }
        return;
    }
    int wave = tid >> 6, lane = tid & 63;
    int t = blockIdx.x * 4 + wave;
    int s0 = tslot[t * 2], s1 = tslot[t * 2 + 1];
    float g0 = tw[t * 2], g1 = tw[t * 2 + 1];
    const ushort4* r0 = (const ushort4*)(obuf + (size_t)s0 * NEMBD);
    const ushort4* r1 = (const ushort4*)(obuf + (size_t)s1 * NEMBD);
    float4* o4 = (float4*)(out + (size_t)t * NEMBD);
    #pragma unroll
    for (int j = 0; j < 3; ++j) {
        int c = j * 64 + lane;
        ushort4 a = r0[c], b = r1[c];
        float4 o;
        o.x = g0 * bf2f(a.x) + g1 * bf2f(b.x);
        o.y = g0 * bf2f(a.y) + g1 * bf2f(b.y);
        o.z = g0 * bf2f(a.z) + g1 * bf2f(b.z);
        o.w = g0 * bf2f(a.w) + g1 * bf2f(b.w);
        o4[c] = o;
    }
}

extern "C" void kernel_launch(void* const* d_in, const int* in_sizes, int n_in,
                              void* d_out, int out_size, void* d_ws, size_t ws_size,
                              hipStream_t stream) {
    const float* x   = (const float*)d_in[0];
    const float* WgP = (const float*)d_in[1];
    const float* WgQ = (const float*)d_in[2];
    const float* Wfc = (const float*)d_in[3];
    const float* Wpj = (const float*)d_in[4];
    float* out = (float*)d_out;

    char* ws = (char*)d_ws;
    unsigned short* xbf  = (unsigned short*)(ws + WS_XBF);
    float* gates = (float*)(ws + WS_GATES);
    int*   te    = (int*)(ws + WS_TE);
    float* tw    = (float*)(ws + WS_TW);
    float* klt   = (float*)(ws + WS_KL);
    int*   ctrl  = (int*)(ws + WS_CTRL);
    int*   stok  = (int*)(ws + WS_STOK);
    int*   tslot = (int*)(ws + WS_TSLOT);
    unsigned short* WfcT = (unsigned short*)(ws + WS_WFCT);
    unsigned short* WpT  = (unsigned short*)(ws + WS_WPT);
    unsigned short* H    = (unsigned short*)(ws + WS_H);
    unsigned short* obuf = (unsigned short*)(ws + WS_OBUF);

    k_front<<<512 + 2304 + 2304, 256, 0, stream>>>(
        x, WgP, WgQ, Wfc, Wpj, WfcT, WpT, xbf, gates, te, tw, klt);
    k_sched<<<1, 256, 0, stream>>>(te, ctrl, stok, tslot);
    k_gemm1<<<MAXT1 * NT1, 256, 0, stream>>>(xbf, WfcT, ctrl, stok, H);
    k_gemm2<<<MAXT2 * NT2, 256, 0, stream>>>(H, WpT, ctrl, obuf);
    k_finish<<<513, 256, 0, stream>>>(obuf, tslot, tw, gates, klt, ctrl, out);
}